// Round 1
// baseline (2685.064 us; speedup 1.0000x reference)
//
#include <hip/hip_runtime.h>
#include <math.h>

#define B_   2
#define T_   2048
#define C_   1024
#define H_   16
#define HD_  64
#define WIN_ 512

// ---------------- RoPE table: cos/sin (T, 32) ----------------
__global__ void rope_table_k(float* __restrict__ cosT, float* __restrict__ sinT) {
    int gid = blockIdx.x * blockDim.x + threadIdx.x;
    if (gid >= T_ * 32) return;
    int t = gid >> 5, j = gid & 31;
    float inv = powf(10000.0f, -(float)j / 32.0f);
    float f = (float)t * inv;
    cosT[gid] = cosf(f);
    sinT[gid] = sinf(f);
}

// ---------------- RoPE apply in-place on q,k parts of qkv ----------------
// qkv layout: [(b*T + t), 3072] with col = part*1024 + h*64 + d
__global__ void rope_apply_k(float* __restrict__ qkv,
                             const float* __restrict__ cosT,
                             const float* __restrict__ sinT) {
    int gid = blockIdx.x * blockDim.x + threadIdx.x;   // B*T * 2 * H * 32 = 4194304
    int p  = gid & 1023;            // pair index within (b,t): part(2) x h(16) x j(32)
    int bt = gid >> 10;             // [0, B*T)
    if (bt >= B_ * T_) return;
    int j    = p & 31;
    int h    = (p >> 5) & 15;
    int part = p >> 9;              // 0 = q, 1 = k
    size_t base = (size_t)bt * 3072 + (size_t)part * 1024 + h * 64 + 2 * j;
    int t = bt % T_;
    float c = cosT[t * 32 + j];
    float s = sinT[t * 32 + j];
    float x0 = qkv[base];
    float x1 = qkv[base + 1];
    qkv[base]     = x0 * c - x1 * s;
    qkv[base + 1] = x1 * c + x0 * s;
}

// ---------------- fp32 tiled GEMM: C[m,n] = sum_k A[m,k]*B[n,k] (+bias[n]) ----
// A: M x K row-major, Bm: N x K row-major. M,N multiples of 128, K multiple of 16.
#define TILE 128
#define BK   16

__global__ __launch_bounds__(256) void gemm_nt_kernel(
        const float* __restrict__ A, const float* __restrict__ Bm,
        const float* __restrict__ bias, float* __restrict__ C,
        int M, int N, int K)
{
    __shared__ float As[BK][TILE + 1];
    __shared__ float Bs[BK][TILE + 1];
    const int tid = threadIdx.x;
    const int bm0 = blockIdx.y * TILE;
    const int bn0 = blockIdx.x * TILE;
    const int tx = tid & 15;        // 0..15 -> col group
    const int ty = tid >> 4;        // 0..15 -> row group

    float acc[8][8] = {};

    for (int k0 = 0; k0 < K; k0 += BK) {
        // stage A and B tiles: each 128 rows x 16 k = 512 float4, 2 per thread
        #pragma unroll
        for (int l = 0; l < 2; ++l) {
            int slot = tid + l * 256;            // [0,512)
            int row  = slot >> 2;                // [0,128)
            int k4   = (slot & 3) << 2;          // {0,4,8,12}
            float4 av = *(const float4*)&A[(size_t)(bm0 + row) * K + k0 + k4];
            As[k4 + 0][row] = av.x; As[k4 + 1][row] = av.y;
            As[k4 + 2][row] = av.z; As[k4 + 3][row] = av.w;
            float4 bv = *(const float4*)&Bm[(size_t)(bn0 + row) * K + k0 + k4];
            Bs[k4 + 0][row] = bv.x; Bs[k4 + 1][row] = bv.y;
            Bs[k4 + 2][row] = bv.z; Bs[k4 + 3][row] = bv.w;
        }
        __syncthreads();
        #pragma unroll
        for (int k = 0; k < BK; ++k) {
            float a[8], b[8];
            #pragma unroll
            for (int i = 0; i < 8; ++i) a[i] = As[k][ty * 8 + i];
            #pragma unroll
            for (int j = 0; j < 8; ++j) b[j] = Bs[k][tx * 8 + j];
            #pragma unroll
            for (int i = 0; i < 8; ++i)
                #pragma unroll
                for (int j = 0; j < 8; ++j)
                    acc[i][j] += a[i] * b[j];
        }
        __syncthreads();
    }

    #pragma unroll
    for (int i = 0; i < 8; ++i) {
        int m = bm0 + ty * 8 + i;
        #pragma unroll
        for (int j = 0; j < 8; ++j) {
            int n = bn0 + tx * 8 + j;
            float v = acc[i][j];
            if (bias) v += bias[n];
            C[(size_t)m * N + n] = v;
        }
    }
}

// ---------------- banded causal attention, one wave per query row -----------
// qkv layout [(b*T+t), 3072]; q at col h*64, k at 1024+h*64, v at 2048+h*64.
// y layout [(b*T+t), 1024] with col h*64+d.
__global__ __launch_bounds__(256) void attn_k(const float* __restrict__ qkv,
                                              float* __restrict__ y)
{
    const int lane = threadIdx.x & 63;
    const int wid  = blockIdx.x * 4 + (threadIdx.x >> 6);   // [0, B*H*T)
    const int i = wid % T_;
    const int h = (wid / T_) % H_;
    const int b = wid / (T_ * H_);

    const size_t rowq = ((size_t)(b * T_ + i)) * 3072 + h * 64;
    const float qd = qkv[rowq + lane];

    int lo = i - WIN_; if (lo < 0) lo = 0;

    float m = -INFINITY, l = 0.f, acc = 0.f;
    for (int j = lo; j <= i; ++j) {
        const size_t rk = ((size_t)(b * T_ + j)) * 3072 + 1024 + h * 64;
        float s = qd * qkv[rk + lane];
        #pragma unroll
        for (int off = 32; off; off >>= 1) s += __shfl_xor(s, off);
        s *= 0.125f;   // 1/sqrt(64)
        float mn   = fmaxf(m, s);
        float corr = __expf(m - mn);
        float p    = __expf(s - mn);
        float vd   = qkv[rk + 1024 + lane];
        l   = l * corr + p;
        acc = acc * corr + p * vd;
        m = mn;
    }
    y[((size_t)(b * T_ + i)) * 1024 + h * 64 + lane] = acc / l;
}

// ---------------- launch ----------------
extern "C" void kernel_launch(void* const* d_in, const int* in_sizes, int n_in,
                              void* d_out, int out_size, void* d_ws, size_t ws_size,
                              hipStream_t stream) {
    const float* x     = (const float*)d_in[0];
    const float* Wqkv  = (const float*)d_in[1];
    const float* Wproj = (const float*)d_in[2];
    const float* bproj = (const float*)d_in[3];
    float* out = (float*)d_out;

    float* ws   = (float*)d_ws;
    float* cosT = ws;                       // T*32
    float* sinT = cosT + T_ * 32;           // T*32
    float* qkv  = sinT + T_ * 32;           // B*T*3072
    float* y    = qkv + (size_t)B_ * T_ * 3 * C_;  // B*T*1024

    rope_table_k<<<(T_ * 32 + 255) / 256, 256, 0, stream>>>(cosT, sinT);

    dim3 g1(3 * C_ / TILE, (B_ * T_) / TILE);
    gemm_nt_kernel<<<g1, 256, 0, stream>>>(x, Wqkv, nullptr, qkv, B_ * T_, 3 * C_, C_);

    rope_apply_k<<<(B_ * T_ * 1024) / 256, 256, 0, stream>>>(qkv, cosT, sinT);

    attn_k<<<(B_ * H_ * T_) / 4, 256, 0, stream>>>(qkv, y);

    dim3 g2(C_ / TILE, (B_ * T_) / TILE);
    gemm_nt_kernel<<<g2, 256, 0, stream>>>(y, Wproj, bproj, out, B_ * T_, C_, C_);
}

// Round 2
// 774.500 us; speedup vs baseline: 3.4668x; 3.4668x over previous
//
#include <hip/hip_runtime.h>
#include <math.h>

#define B_   2
#define T_   2048
#define C_   1024
#define H_   16
#define HD_  64
#define WIN_ 512

typedef __bf16 bf16x8 __attribute__((ext_vector_type(8)));
typedef float  f32x4  __attribute__((ext_vector_type(4)));

__device__ inline f32x4 mfma16(bf16x8 a, bf16x8 b, f32x4 c) {
    return __builtin_amdgcn_mfma_f32_16x16x32_bf16(a, b, c, 0, 0, 0);
}
__device__ inline unsigned short f2b(float f) {
    __bf16 h = (__bf16)f;
    unsigned short u;
    __builtin_memcpy(&u, &h, 2);
    return u;
}

// ---------------- RoPE table: cos/sin (T, 32) ----------------
__global__ void rope_table_k(float* __restrict__ cosT, float* __restrict__ sinT) {
    int gid = blockIdx.x * blockDim.x + threadIdx.x;
    if (gid >= T_ * 32) return;
    int t = gid >> 5, j = gid & 31;
    float inv = powf(10000.0f, -(float)j / 32.0f);
    float f = (float)t * inv;
    cosT[gid] = cosf(f);
    sinT[gid] = sinf(f);
}

// ---------------- RoPE apply in-place on q,k parts of qkv ----------------
__global__ void rope_apply_k(float* __restrict__ qkv,
                             const float* __restrict__ cosT,
                             const float* __restrict__ sinT) {
    int gid = blockIdx.x * blockDim.x + threadIdx.x;
    int p  = gid & 1023;
    int bt = gid >> 10;
    if (bt >= B_ * T_) return;
    int j    = p & 31;
    int h    = (p >> 5) & 15;
    int part = p >> 9;              // 0 = q, 1 = k
    size_t base = (size_t)bt * 3072 + (size_t)part * 1024 + h * 64 + 2 * j;
    int t = bt % T_;
    float c = cosT[t * 32 + j];
    float s = sinT[t * 32 + j];
    float x0 = qkv[base];
    float x1 = qkv[base + 1];
    qkv[base]     = x0 * c - x1 * s;
    qkv[base + 1] = x1 * c + x0 * s;
}

// ---------------- fp32 tiled GEMM: C[m,n] = sum_k A[m,k]*B[n,k] (+bias[n]) ----
#define TILE 128
#define BK   16

__global__ __launch_bounds__(256) void gemm_nt_kernel(
        const float* __restrict__ A, const float* __restrict__ Bm,
        const float* __restrict__ bias, float* __restrict__ C,
        int M, int N, int K)
{
    __shared__ float As[BK][TILE + 1];
    __shared__ float Bs[BK][TILE + 1];
    const int tid = threadIdx.x;
    const int bm0 = blockIdx.y * TILE;
    const int bn0 = blockIdx.x * TILE;
    const int tx = tid & 15;
    const int ty = tid >> 4;

    float acc[8][8] = {};

    for (int k0 = 0; k0 < K; k0 += BK) {
        #pragma unroll
        for (int l = 0; l < 2; ++l) {
            int slot = tid + l * 256;
            int row  = slot >> 2;
            int k4   = (slot & 3) << 2;
            float4 av = *(const float4*)&A[(size_t)(bm0 + row) * K + k0 + k4];
            As[k4 + 0][row] = av.x; As[k4 + 1][row] = av.y;
            As[k4 + 2][row] = av.z; As[k4 + 3][row] = av.w;
            float4 bv = *(const float4*)&Bm[(size_t)(bn0 + row) * K + k0 + k4];
            Bs[k4 + 0][row] = bv.x; Bs[k4 + 1][row] = bv.y;
            Bs[k4 + 2][row] = bv.z; Bs[k4 + 3][row] = bv.w;
        }
        __syncthreads();
        #pragma unroll
        for (int k = 0; k < BK; ++k) {
            float a[8], b[8];
            #pragma unroll
            for (int i = 0; i < 8; ++i) a[i] = As[k][ty * 8 + i];
            #pragma unroll
            for (int j = 0; j < 8; ++j) b[j] = Bs[k][tx * 8 + j];
            #pragma unroll
            for (int i = 0; i < 8; ++i)
                #pragma unroll
                for (int j = 0; j < 8; ++j)
                    acc[i][j] += a[i] * b[j];
        }
        __syncthreads();
    }

    #pragma unroll
    for (int i = 0; i < 8; ++i) {
        int m = bm0 + ty * 8 + i;
        #pragma unroll
        for (int j = 0; j < 8; ++j) {
            int n = bn0 + tx * 8 + j;
            float v = acc[i][j];
            if (bias) v += bias[n];
            C[(size_t)m * N + n] = v;
        }
    }
}

// ---------------- banded flash attention, MFMA bf16 -----------------------
// Block = 256 threads (4 waves); each block: one (b, h, 64-row q tile).
// Wave w owns q rows [q0+w*16, q0+w*16+15]. Key tiles of 64, staged in LDS.
// qkv layout [(b*T+t), 3072]: q at h*64, k at 1024+h*64, v at 2048+h*64.
__global__ __launch_bounds__(256) void attn_k(const float* __restrict__ qkv,
                                              float* __restrict__ y)
{
    __shared__ unsigned short Ks[64 * 72];   // K tile, row j, padded stride 72
    __shared__ unsigned short Vt[64 * 72];   // V tile transposed: row d, col j
    __shared__ unsigned short Ps[64 * 72];   // P tile, row (wave-local q), col j

    const int tid  = threadIdx.x;
    const int lane = tid & 63;
    const int w    = tid >> 6;
    const int c    = lane & 15;      // frag col / row-within-16
    const int g    = lane >> 4;      // frag k-chunk group

    const int qt = blockIdx.x;
    const int h  = blockIdx.y;
    const int b  = blockIdx.z;
    const int q0 = qt * 64;

    // ---- load Q fragments (scaled by 1/sqrt(64)) ----
    bf16x8 qa[2];
    {
        const int qrow = q0 + w * 16 + c;
        const float* qp = qkv + (size_t)(b * T_ + qrow) * 3072 + h * 64 + g * 8;
        #pragma unroll
        for (int ks = 0; ks < 2; ++ks) {
            float4 f0 = *(const float4*)(qp + ks * 32);
            float4 f1 = *(const float4*)(qp + ks * 32 + 4);
            qa[ks][0] = (__bf16)(f0.x * 0.125f);
            qa[ks][1] = (__bf16)(f0.y * 0.125f);
            qa[ks][2] = (__bf16)(f0.z * 0.125f);
            qa[ks][3] = (__bf16)(f0.w * 0.125f);
            qa[ks][4] = (__bf16)(f1.x * 0.125f);
            qa[ks][5] = (__bf16)(f1.y * 0.125f);
            qa[ks][6] = (__bf16)(f1.z * 0.125f);
            qa[ks][7] = (__bf16)(f1.w * 0.125f);
        }
    }

    float m_run[4] = {-1e30f, -1e30f, -1e30f, -1e30f};
    float l_run[4] = {0.f, 0.f, 0.f, 0.f};
    f32x4 o[4] = {};

    const int j_start = (q0 >= WIN_) ? (q0 - WIN_) : 0;

    for (int j0 = j_start; j0 <= q0; j0 += 64) {
        __syncthreads();   // previous iteration's LDS reads complete
        // ---- stage K (row-major) and V (transposed) as bf16 ----
        #pragma unroll
        for (int it = 0; it < 4; ++it) {
            int slot = tid + it * 256;          // [0,1024)
            int row  = slot >> 4;               // key j-local [0,64)
            int d4   = (slot & 15) << 2;        // [0,64) step 4
            const float* kp = qkv + (size_t)(b * T_ + j0 + row) * 3072 + 1024 + h * 64 + d4;
            float4 kv = *(const float4*)kp;
            ushort4 kb;
            kb.x = f2b(kv.x); kb.y = f2b(kv.y); kb.z = f2b(kv.z); kb.w = f2b(kv.w);
            *(ushort4*)&Ks[row * 72 + d4] = kb;
            float4 vv = *(const float4*)(kp + 1024);
            Vt[(d4 + 0) * 72 + row] = f2b(vv.x);
            Vt[(d4 + 1) * 72 + row] = f2b(vv.y);
            Vt[(d4 + 2) * 72 + row] = f2b(vv.z);
            Vt[(d4 + 3) * 72 + row] = f2b(vv.w);
        }
        __syncthreads();

        // ---- S = Q K^T (already scaled via Q) ----
        f32x4 sc[4];
        #pragma unroll
        for (int nt = 0; nt < 4; ++nt) {
            const bf16x8 b0 = *(const bf16x8*)&Ks[(nt * 16 + c) * 72 + g * 8];
            const bf16x8 b1 = *(const bf16x8*)&Ks[(nt * 16 + c) * 72 + 32 + g * 8];
            f32x4 s = {0.f, 0.f, 0.f, 0.f};
            s = mfma16(qa[0], b0, s);
            s = mfma16(qa[1], b1, s);
            sc[nt] = s;
        }

        // ---- mask + online softmax (row = q0 + w*16 + g*4 + reg) ----
        float corr[4];
        #pragma unroll
        for (int reg = 0; reg < 4; ++reg) {
            const int i_abs = q0 + w * 16 + g * 4 + reg;
            float best = -1e30f;
            #pragma unroll
            for (int nt = 0; nt < 4; ++nt) {
                int j_abs = j0 + nt * 16 + c;
                float sv = sc[nt][reg];
                bool ok = (j_abs <= i_abs) && (i_abs - j_abs <= WIN_);
                sv = ok ? sv : -1e30f;
                sc[nt][reg] = sv;
                best = fmaxf(best, sv);
            }
            #pragma unroll
            for (int off = 1; off < 16; off <<= 1)
                best = fmaxf(best, __shfl_xor(best, off));
            float mn = fmaxf(m_run[reg], best);
            corr[reg] = __expf(m_run[reg] - mn);
            m_run[reg] = mn;
            float sp = 0.f;
            #pragma unroll
            for (int nt = 0; nt < 4; ++nt) {
                float p = __expf(sc[nt][reg] - mn);
                sp += p;
                Ps[(w * 16 + g * 4 + reg) * 72 + nt * 16 + c] = f2b(p);
            }
            #pragma unroll
            for (int off = 1; off < 16; off <<= 1)
                sp += __shfl_xor(sp, off);
            l_run[reg] = l_run[reg] * corr[reg] + sp;
        }
        #pragma unroll
        for (int dt = 0; dt < 4; ++dt)
            #pragma unroll
            for (int reg = 0; reg < 4; ++reg)
                o[dt][reg] *= corr[reg];

        __syncthreads();   // P visible (and K/V reads done before restage)

        // ---- O += P V ----
        const bf16x8 pa0 = *(const bf16x8*)&Ps[(w * 16 + c) * 72 + g * 8];
        const bf16x8 pa1 = *(const bf16x8*)&Ps[(w * 16 + c) * 72 + 32 + g * 8];
        #pragma unroll
        for (int dt = 0; dt < 4; ++dt) {
            const bf16x8 vb0 = *(const bf16x8*)&Vt[(dt * 16 + c) * 72 + g * 8];
            const bf16x8 vb1 = *(const bf16x8*)&Vt[(dt * 16 + c) * 72 + 32 + g * 8];
            o[dt] = mfma16(pa0, vb0, o[dt]);
            o[dt] = mfma16(pa1, vb1, o[dt]);
        }
    }

    // ---- write y[(b*T + i), h*64 + d] ----
    #pragma unroll
    for (int dt = 0; dt < 4; ++dt)
        #pragma unroll
        for (int reg = 0; reg < 4; ++reg) {
            size_t row = (size_t)(b * T_ + q0 + w * 16 + g * 4 + reg);
            y[row * 1024 + h * 64 + dt * 16 + c] = o[dt][reg] / l_run[reg];
        }
}

// ---------------- launch ----------------
extern "C" void kernel_launch(void* const* d_in, const int* in_sizes, int n_in,
                              void* d_out, int out_size, void* d_ws, size_t ws_size,
                              hipStream_t stream) {
    const float* x     = (const float*)d_in[0];
    const float* Wqkv  = (const float*)d_in[1];
    const float* Wproj = (const float*)d_in[2];
    const float* bproj = (const float*)d_in[3];
    float* out = (float*)d_out;

    float* ws   = (float*)d_ws;
    float* cosT = ws;
    float* sinT = cosT + T_ * 32;
    float* qkv  = sinT + T_ * 32;
    float* y    = qkv + (size_t)B_ * T_ * 3 * C_;

    rope_table_k<<<(T_ * 32 + 255) / 256, 256, 0, stream>>>(cosT, sinT);

    dim3 g1(3 * C_ / TILE, (B_ * T_) / TILE);
    gemm_nt_kernel<<<g1, 256, 0, stream>>>(x, Wqkv, nullptr, qkv, B_ * T_, 3 * C_, C_);

    rope_apply_k<<<(B_ * T_ * 1024) / 256, 256, 0, stream>>>(qkv, cosT, sinT);

    dim3 ga(T_ / 64, H_, B_);
    attn_k<<<ga, 256, 0, stream>>>(qkv, y);

    dim3 g2(C_ / TILE, (B_ * T_) / TILE);
    gemm_nt_kernel<<<g2, 256, 0, stream>>>(y, Wproj, bproj, out, B_ * T_, C_, C_);
}

// Round 3
// 145.034 us; speedup vs baseline: 18.5133x; 5.3401x over previous
//
#include <hip/hip_runtime.h>
#include <math.h>

#define B_   2
#define T_   2048
#define C_   1024
#define H_   16
#define HD_  64
#define WIN_ 512
#define BT_  (B_ * T_)

typedef __bf16 bf16x8 __attribute__((ext_vector_type(8)));
typedef float  f32x4  __attribute__((ext_vector_type(4)));

__device__ __forceinline__ f32x4 mfma16(bf16x8 a, bf16x8 b, f32x4 c) {
    return __builtin_amdgcn_mfma_f32_16x16x32_bf16(a, b, c, 0, 0, 0);
}
__device__ __forceinline__ unsigned short f2b(float f) {
    __bf16 h = (__bf16)f;
    unsigned short u;
    __builtin_memcpy(&u, &h, 2);
    return u;
}
__device__ __forceinline__ void async_copy16(__bf16* lds, const __bf16* g) {
    __builtin_amdgcn_global_load_lds(
        (const __attribute__((address_space(1))) void*)g,
        (__attribute__((address_space(3))) void*)lds,
        16, 0, 0);
}

// ---------------- RoPE table: cos/sin (T, 32) ----------------
__global__ void rope_table_k(float* __restrict__ cosT, float* __restrict__ sinT) {
    int gid = blockIdx.x * blockDim.x + threadIdx.x;
    if (gid >= T_ * 32) return;
    int t = gid >> 5, j = gid & 31;
    float inv = powf(10000.0f, -(float)j / 32.0f);
    float f = (float)t * inv;
    cosT[gid] = cosf(f);
    sinT[gid] = sinf(f);
}

// ---------------- fp32 -> bf16 convert (8 elems/thread) ----------------
__global__ void cvt_bf16_k(const float* __restrict__ src, __bf16* __restrict__ dst, int n8) {
    int gid = blockIdx.x * blockDim.x + threadIdx.x;
    if (gid >= n8) return;
    float4 a = *(const float4*)&src[(size_t)gid * 8];
    float4 b = *(const float4*)&src[(size_t)gid * 8 + 4];
    bf16x8 o;
    o[0] = (__bf16)a.x; o[1] = (__bf16)a.y; o[2] = (__bf16)a.z; o[3] = (__bf16)a.w;
    o[4] = (__bf16)b.x; o[5] = (__bf16)b.y; o[6] = (__bf16)b.z; o[7] = (__bf16)b.w;
    *(bf16x8*)&dst[(size_t)gid * 8] = o;
}

// ---------------- RoPE apply in-place on bf16 qkv (q,k parts) --------------
// qkv layout [(b*T+t), 3072]; thread handles 4 pairs (8 contiguous bf16).
__global__ void rope_apply_k(__bf16* __restrict__ qkv,
                             const float* __restrict__ cosT,
                             const float* __restrict__ sinT) {
    int gid = blockIdx.x * blockDim.x + threadIdx.x;   // [0, B*T*2*16*8)
    int qd   = gid & 7;
    int h    = (gid >> 3) & 15;
    int part = (gid >> 7) & 1;
    int bt   = gid >> 8;
    if (bt >= BT_) return;
    int t = bt & (T_ - 1);
    size_t base = (size_t)bt * 3072 + part * 1024 + h * 64 + qd * 8;
    bf16x8 v = *(bf16x8*)&qkv[base];
    float4 c4 = *(const float4*)&cosT[t * 32 + qd * 4];
    float4 s4 = *(const float4*)&sinT[t * 32 + qd * 4];
    bf16x8 o;
    float x0, x1;
    x0 = (float)v[0]; x1 = (float)v[1];
    o[0] = (__bf16)(x0 * c4.x - x1 * s4.x); o[1] = (__bf16)(x1 * c4.x + x0 * s4.x);
    x0 = (float)v[2]; x1 = (float)v[3];
    o[2] = (__bf16)(x0 * c4.y - x1 * s4.y); o[3] = (__bf16)(x1 * c4.y + x0 * s4.y);
    x0 = (float)v[4]; x1 = (float)v[5];
    o[4] = (__bf16)(x0 * c4.z - x1 * s4.z); o[5] = (__bf16)(x1 * c4.z + x0 * s4.z);
    x0 = (float)v[6]; x1 = (float)v[7];
    o[6] = (__bf16)(x0 * c4.w - x1 * s4.w); o[7] = (__bf16)(x1 * c4.w + x0 * s4.w);
    *(bf16x8*)&qkv[base] = o;
}

// ---------------- bf16 MFMA GEMM (m97 structure): C = A @ B^T (+bias) ------
// A: M x K bf16 row-major, Bm: N x K bf16 row-major. M,N % 128 == 0, K % 32 == 0.
template<bool OUT_BF16>
__global__ __launch_bounds__(256) void gemm_bt_mfma(
        const __bf16* __restrict__ A, const __bf16* __restrict__ Bm,
        const float* __restrict__ bias, void* __restrict__ Cv,
        int M, int N, int K)
{
    __shared__ __bf16 As[128 * 32];
    __shared__ __bf16 Bs[128 * 32];
    const int tid  = threadIdx.x;
    const int w    = tid >> 6;
    const int lane = tid & 63;
    const int c    = lane & 15;
    const int g    = lane >> 4;
    const int bm0  = blockIdx.y * 128;
    const int bn0  = blockIdx.x * 128;
    const int wm0  = (w >> 1) * 64;
    const int wn0  = (w & 1) * 64;

    f32x4 acc[4][4] = {};

    for (int k0 = 0; k0 < K; k0 += 32) {
        #pragma unroll
        for (int it = 0; it < 2; ++it) {
            int slot = it * 256 + tid;           // [0,512)
            int r    = slot >> 2;                // [0,128)
            int c8   = (slot & 3) * 8;           // {0,8,16,24}
            async_copy16(&As[slot * 8], &A[(size_t)(bm0 + r) * K + k0 + c8]);
            async_copy16(&Bs[slot * 8], &Bm[(size_t)(bn0 + r) * K + k0 + c8]);
        }
        __syncthreads();
        bf16x8 af[4], bfr[4];
        #pragma unroll
        for (int m = 0; m < 4; ++m)
            af[m] = *(const bf16x8*)&As[(wm0 + m * 16 + c) * 32 + g * 8];
        #pragma unroll
        for (int n = 0; n < 4; ++n)
            bfr[n] = *(const bf16x8*)&Bs[(wn0 + n * 16 + c) * 32 + g * 8];
        #pragma unroll
        for (int m = 0; m < 4; ++m)
            #pragma unroll
            for (int n = 0; n < 4; ++n)
                acc[m][n] = mfma16(af[m], bfr[n], acc[m][n]);
        __syncthreads();
    }

    #pragma unroll
    for (int m = 0; m < 4; ++m) {
        int rr = bm0 + wm0 + m * 16 + g * 4;
        #pragma unroll
        for (int n = 0; n < 4; ++n) {
            int cc = bn0 + wn0 + n * 16 + c;
            float bv = (!OUT_BF16 && bias) ? bias[cc] : 0.f;
            #pragma unroll
            for (int r2 = 0; r2 < 4; ++r2) {
                float v = acc[m][n][r2] + bv;
                if (OUT_BF16) ((__bf16*)Cv)[(size_t)(rr + r2) * N + cc] = (__bf16)v;
                else          ((float*)Cv)[(size_t)(rr + r2) * N + cc] = v;
            }
        }
    }
}

// ---------------- banded flash attention, MFMA bf16 (bf16 qkv in, bf16 y out)
__global__ __launch_bounds__(256) void attn_k(const __bf16* __restrict__ qkv,
                                              __bf16* __restrict__ y)
{
    __shared__ unsigned short Ks[64 * 72];
    __shared__ unsigned short Vt[64 * 72];
    __shared__ unsigned short Ps[64 * 72];

    const int tid  = threadIdx.x;
    const int lane = tid & 63;
    const int w    = tid >> 6;
    const int c    = lane & 15;
    const int g    = lane >> 4;

    const int q0 = blockIdx.x * 64;
    const int h  = blockIdx.y;
    const int b  = blockIdx.z;

    // ---- load Q fragments (unscaled; scale applied to scores) ----
    bf16x8 qa[2];
    {
        const int qrow = q0 + w * 16 + c;
        const __bf16* qp = qkv + (size_t)(b * T_ + qrow) * 3072 + h * 64 + g * 8;
        qa[0] = *(const bf16x8*)qp;
        qa[1] = *(const bf16x8*)(qp + 32);
    }

    float m_run[4] = {-1e30f, -1e30f, -1e30f, -1e30f};
    float l_run[4] = {0.f, 0.f, 0.f, 0.f};
    f32x4 o[4] = {};

    const int j_start = (q0 >= WIN_) ? (q0 - WIN_) : 0;

    for (int j0 = j_start; j0 <= q0; j0 += 64) {
        __syncthreads();
        // ---- stage K (row-major) and V (transposed), both already bf16 ----
        #pragma unroll
        for (int it = 0; it < 4; ++it) {
            int slot = tid + it * 256;          // [0,1024)
            int row  = slot >> 4;               // [0,64)
            int d4   = (slot & 15) << 2;        // [0,64) step 4
            const __bf16* kp = qkv + (size_t)(b * T_ + j0 + row) * 3072 + 1024 + h * 64 + d4;
            *(ushort4*)&Ks[row * 72 + d4] = *(const ushort4*)kp;
            ushort4 vv = *(const ushort4*)(kp + 1024);
            Vt[(d4 + 0) * 72 + row] = vv.x;
            Vt[(d4 + 1) * 72 + row] = vv.y;
            Vt[(d4 + 2) * 72 + row] = vv.z;
            Vt[(d4 + 3) * 72 + row] = vv.w;
        }
        __syncthreads();

        // ---- S = Q K^T ----
        f32x4 sc[4];
        #pragma unroll
        for (int nt = 0; nt < 4; ++nt) {
            const bf16x8 b0 = *(const bf16x8*)&Ks[(nt * 16 + c) * 72 + g * 8];
            const bf16x8 b1 = *(const bf16x8*)&Ks[(nt * 16 + c) * 72 + 32 + g * 8];
            f32x4 s = {0.f, 0.f, 0.f, 0.f};
            s = mfma16(qa[0], b0, s);
            s = mfma16(qa[1], b1, s);
            sc[nt] = s;
        }

        // ---- mask + scale + online softmax (row = q0 + w*16 + g*4 + reg) ----
        float corr[4];
        #pragma unroll
        for (int reg = 0; reg < 4; ++reg) {
            const int i_abs = q0 + w * 16 + g * 4 + reg;
            float best = -1e30f;
            #pragma unroll
            for (int nt = 0; nt < 4; ++nt) {
                int j_abs = j0 + nt * 16 + c;
                float sv = sc[nt][reg] * 0.125f;
                bool ok = (j_abs <= i_abs) && (i_abs - j_abs <= WIN_);
                sv = ok ? sv : -1e30f;
                sc[nt][reg] = sv;
                best = fmaxf(best, sv);
            }
            #pragma unroll
            for (int off = 1; off < 16; off <<= 1)
                best = fmaxf(best, __shfl_xor(best, off));
            float mn = fmaxf(m_run[reg], best);
            corr[reg] = __expf(m_run[reg] - mn);
            m_run[reg] = mn;
            float sp = 0.f;
            #pragma unroll
            for (int nt = 0; nt < 4; ++nt) {
                float p = __expf(sc[nt][reg] - mn);
                sp += p;
                Ps[(w * 16 + g * 4 + reg) * 72 + nt * 16 + c] = f2b(p);
            }
            #pragma unroll
            for (int off = 1; off < 16; off <<= 1)
                sp += __shfl_xor(sp, off);
            l_run[reg] = l_run[reg] * corr[reg] + sp;
        }
        #pragma unroll
        for (int dt = 0; dt < 4; ++dt)
            #pragma unroll
            for (int reg = 0; reg < 4; ++reg)
                o[dt][reg] *= corr[reg];

        __syncthreads();

        // ---- O += P V ----
        const bf16x8 pa0 = *(const bf16x8*)&Ps[(w * 16 + c) * 72 + g * 8];
        const bf16x8 pa1 = *(const bf16x8*)&Ps[(w * 16 + c) * 72 + 32 + g * 8];
        #pragma unroll
        for (int dt = 0; dt < 4; ++dt) {
            const bf16x8 vb0 = *(const bf16x8*)&Vt[(dt * 16 + c) * 72 + g * 8];
            const bf16x8 vb1 = *(const bf16x8*)&Vt[(dt * 16 + c) * 72 + 32 + g * 8];
            o[dt] = mfma16(pa0, vb0, o[dt]);
            o[dt] = mfma16(pa1, vb1, o[dt]);
        }
    }

    // ---- write y (bf16) ----
    float inv_l[4];
    #pragma unroll
    for (int reg = 0; reg < 4; ++reg) inv_l[reg] = 1.f / l_run[reg];
    #pragma unroll
    for (int dt = 0; dt < 4; ++dt)
        #pragma unroll
        for (int reg = 0; reg < 4; ++reg) {
            size_t row = (size_t)(b * T_ + q0 + w * 16 + g * 4 + reg);
            y[row * 1024 + h * 64 + dt * 16 + c] = (__bf16)(o[dt][reg] * inv_l[reg]);
        }
}

// ---------------- launch ----------------
extern "C" void kernel_launch(void* const* d_in, const int* in_sizes, int n_in,
                              void* d_out, int out_size, void* d_ws, size_t ws_size,
                              hipStream_t stream) {
    const float* x     = (const float*)d_in[0];
    const float* Wqkv  = (const float*)d_in[1];
    const float* Wproj = (const float*)d_in[2];
    const float* bproj = (const float*)d_in[3];
    float* out = (float*)d_out;

    char* p = (char*)d_ws;
    float*  cosT   = (float*)p;   p += (size_t)T_ * 32 * 4;
    float*  sinT   = (float*)p;   p += (size_t)T_ * 32 * 4;
    __bf16* xb     = (__bf16*)p;  p += (size_t)BT_ * 1024 * 2;
    __bf16* Wqkvb  = (__bf16*)p;  p += (size_t)3072 * 1024 * 2;
    __bf16* Wprojb = (__bf16*)p;  p += (size_t)1024 * 1024 * 2;
    __bf16* qkvb   = (__bf16*)p;  p += (size_t)BT_ * 3072 * 2;
    __bf16* yb     = (__bf16*)p;  p += (size_t)BT_ * 1024 * 2;

    rope_table_k<<<(T_ * 32) / 256, 256, 0, stream>>>(cosT, sinT);

    cvt_bf16_k<<<(BT_ * 1024 / 8) / 256, 256, 0, stream>>>(x, xb, BT_ * 1024 / 8);
    cvt_bf16_k<<<(3072 * 1024 / 8) / 256, 256, 0, stream>>>(Wqkv, Wqkvb, 3072 * 1024 / 8);
    cvt_bf16_k<<<(1024 * 1024 / 8) / 256, 256, 0, stream>>>(Wproj, Wprojb, 1024 * 1024 / 8);

    dim3 g1(3072 / 128, BT_ / 128);
    gemm_bt_mfma<true><<<g1, 256, 0, stream>>>(xb, Wqkvb, nullptr, qkvb, BT_, 3072, 1024);

    rope_apply_k<<<(BT_ * 256) / 256, 256, 0, stream>>>(qkvb, cosT, sinT);

    dim3 ga(T_ / 64, H_, B_);
    attn_k<<<ga, 256, 0, stream>>>(qkvb, yb);

    dim3 g2(1024 / 128, BT_ / 128);
    gemm_bt_mfma<false><<<g2, 256, 0, stream>>>(yb, Wprojb, bproj, out, BT_, 1024, 1024);
}

// Round 4
// 139.343 us; speedup vs baseline: 19.2695x; 1.0408x over previous
//
#include <hip/hip_runtime.h>
#include <math.h>

#define B_   2
#define T_   2048
#define C_   1024
#define H_   16
#define HD_  64
#define WIN_ 512
#define BT_  (B_ * T_)

typedef __bf16 bf16x8 __attribute__((ext_vector_type(8)));
typedef float  f32x4  __attribute__((ext_vector_type(4)));
typedef unsigned int u32x2 __attribute__((ext_vector_type(2)));

__device__ __forceinline__ f32x4 mfma16(bf16x8 a, bf16x8 b, f32x4 c) {
    return __builtin_amdgcn_mfma_f32_16x16x32_bf16(a, b, c, 0, 0, 0);
}
__device__ __forceinline__ unsigned short f2b(float f) {
    __bf16 h = (__bf16)f;
    unsigned short u;
    __builtin_memcpy(&u, &h, 2);
    return u;
}
__device__ __forceinline__ void async_copy16(__bf16* lds, const __bf16* g) {
    __builtin_amdgcn_global_load_lds(
        (const __attribute__((address_space(1))) void*)g,
        (__attribute__((address_space(3))) void*)lds,
        16, 0, 0);
}

// hardware transpose read: lane l delivers column (l&15) of the 4x16 bf16
// tile at (per-lane vaddr); OFFLIT is a literal byte offset string.
#define TR16(dst, va, OFFLIT) \
    asm volatile("ds_read_b64_tr_b16 %0, %1 offset:" OFFLIT : "=v"(dst) : "v"(va))

__device__ __forceinline__ bf16x8 combine_tr(u32x2 a, u32x2 b) {
    union { unsigned u[4]; bf16x8 v; } x;
    x.u[0] = a[0]; x.u[1] = a[1]; x.u[2] = b[0]; x.u[3] = b[1];
    return x.v;
}

// ---------------- RoPE table: cos/sin (T, 32) ----------------
__global__ void rope_table_k(float* __restrict__ cosT, float* __restrict__ sinT) {
    int gid = blockIdx.x * blockDim.x + threadIdx.x;
    if (gid >= T_ * 32) return;
    int t = gid >> 5, j = gid & 31;
    float inv = powf(10000.0f, -(float)j / 32.0f);
    float f = (float)t * inv;
    cosT[gid] = cosf(f);
    sinT[gid] = sinf(f);
}

// ---------------- fp32 -> bf16 convert (8 elems/thread) ----------------
__global__ void cvt_bf16_k(const float* __restrict__ src, __bf16* __restrict__ dst, int n8) {
    int gid = blockIdx.x * blockDim.x + threadIdx.x;
    if (gid >= n8) return;
    float4 a = *(const float4*)&src[(size_t)gid * 8];
    float4 b = *(const float4*)&src[(size_t)gid * 8 + 4];
    bf16x8 o;
    o[0] = (__bf16)a.x; o[1] = (__bf16)a.y; o[2] = (__bf16)a.z; o[3] = (__bf16)a.w;
    o[4] = (__bf16)b.x; o[5] = (__bf16)b.y; o[6] = (__bf16)b.z; o[7] = (__bf16)b.w;
    *(bf16x8*)&dst[(size_t)gid * 8] = o;
}

// ---------------- bf16 MFMA GEMM (m97 structure): C = A @ B^T (+bias) ------
// ROPE: fused rotary embedding on cols < 2048 (q,k) before bf16 store.
template<bool OUT_BF16, bool ROPE>
__global__ __launch_bounds__(256) void gemm_bt_mfma(
        const __bf16* __restrict__ A, const __bf16* __restrict__ Bm,
        const float* __restrict__ bias, void* __restrict__ Cv,
        int M, int N, int K,
        const float* __restrict__ cosT, const float* __restrict__ sinT)
{
    __shared__ __bf16 As[128 * 32];
    __shared__ __bf16 Bs[128 * 32];
    const int tid  = threadIdx.x;
    const int w    = tid >> 6;
    const int lane = tid & 63;
    const int c    = lane & 15;
    const int g    = lane >> 4;
    const int bm0  = blockIdx.y * 128;
    const int bn0  = blockIdx.x * 128;
    const int wm0  = (w >> 1) * 64;
    const int wn0  = (w & 1) * 64;

    f32x4 acc[4][4] = {};

    for (int k0 = 0; k0 < K; k0 += 32) {
        #pragma unroll
        for (int it = 0; it < 2; ++it) {
            int slot = it * 256 + tid;
            int r    = slot >> 2;
            int c8   = (slot & 3) * 8;
            async_copy16(&As[slot * 8], &A[(size_t)(bm0 + r) * K + k0 + c8]);
            async_copy16(&Bs[slot * 8], &Bm[(size_t)(bn0 + r) * K + k0 + c8]);
        }
        __syncthreads();
        bf16x8 af[4], bfr[4];
        #pragma unroll
        for (int m = 0; m < 4; ++m)
            af[m] = *(const bf16x8*)&As[(wm0 + m * 16 + c) * 32 + g * 8];
        #pragma unroll
        for (int n = 0; n < 4; ++n)
            bfr[n] = *(const bf16x8*)&Bs[(wn0 + n * 16 + c) * 32 + g * 8];
        #pragma unroll
        for (int m = 0; m < 4; ++m)
            #pragma unroll
            for (int n = 0; n < 4; ++n)
                acc[m][n] = mfma16(af[m], bfr[n], acc[m][n]);
        __syncthreads();
    }

    if (ROPE) {
        #pragma unroll
        for (int m = 0; m < 4; ++m) {
            #pragma unroll
            for (int r2 = 0; r2 < 4; ++r2) {
                const int row = bm0 + wm0 + m * 16 + g * 4 + r2;
                const int t = row & (T_ - 1);
                #pragma unroll
                for (int n = 0; n < 4; ++n) {
                    const int cbase = bn0 + wn0 + n * 16;
                    const int cc = cbase + c;
                    float v = acc[m][n][r2];
                    float outv;
                    if (cbase < 2048) {   // q or k region: rotate (uniform branch)
                        float prt = __shfl_xor(v, 1);
                        int jj = (cc & 63) >> 1;
                        float cs = cosT[t * 32 + jj];
                        float sn = sinT[t * 32 + jj];
                        outv = (cc & 1) ? (v * cs + prt * sn) : (v * cs - prt * sn);
                    } else {
                        outv = v;
                    }
                    ((__bf16*)Cv)[(size_t)row * N + cc] = (__bf16)outv;
                }
            }
        }
    } else {
        #pragma unroll
        for (int m = 0; m < 4; ++m) {
            int rr = bm0 + wm0 + m * 16 + g * 4;
            #pragma unroll
            for (int n = 0; n < 4; ++n) {
                int cc = bn0 + wn0 + n * 16 + c;
                float bv = (!OUT_BF16 && bias) ? bias[cc] : 0.f;
                #pragma unroll
                for (int r2 = 0; r2 < 4; ++r2) {
                    float v = acc[m][n][r2] + bv;
                    if (OUT_BF16) ((__bf16*)Cv)[(size_t)(rr + r2) * N + cc] = (__bf16)v;
                    else          ((float*)Cv)[(size_t)(rr + r2) * N + cc] = v;
                }
            }
        }
    }
}

// ---------------- banded flash attention, MFMA bf16 ------------------------
// K: [64][72] row-major (pad 72 kills b128-read conflicts).
// V: 4 column-blocks [64][16], block stride 1040 shorts (pad 16) -> stage
//    writes conflict-free; PV B-fragments via ds_read_b64_tr_b16.
// P: [64][72], wave-local (no barrier needed between write and read).
__global__ __launch_bounds__(256) void attn_k(const __bf16* __restrict__ qkv,
                                              __bf16* __restrict__ y)
{
    __shared__ __align__(16) unsigned short Ks[64 * 72];
    __shared__ __align__(16) unsigned short Ps[64 * 72];
    __shared__ __align__(16) unsigned short Vs[4 * 1040];

    const int tid  = threadIdx.x;
    const int lane = tid & 63;
    const int w    = tid >> 6;
    const int c    = lane & 15;
    const int g    = lane >> 4;

    const int q0 = blockIdx.x * 64;
    const int h  = blockIdx.y;
    const int b  = blockIdx.z;

    // ---- Q fragments, pre-scaled by 1/sqrt(64) (exact exponent shift) ----
    bf16x8 qa[2];
    {
        const int qrow = q0 + w * 16 + c;
        const __bf16* qp = qkv + (size_t)(b * T_ + qrow) * 3072 + h * 64 + g * 8;
        bf16x8 r0 = *(const bf16x8*)qp;
        bf16x8 r1 = *(const bf16x8*)(qp + 32);
        #pragma unroll
        for (int e = 0; e < 8; ++e) {
            qa[0][e] = (__bf16)((float)r0[e] * 0.125f);
            qa[1][e] = (__bf16)((float)r1[e] * 0.125f);
        }
    }

    float m_run[4] = {-1e30f, -1e30f, -1e30f, -1e30f};
    float l_run[4] = {0.f, 0.f, 0.f, 0.f};   // per-lane partial (cols c of each nt)
    f32x4 o[4] = {};

    unsigned vs_lane;
    {
        auto* p3 = (__attribute__((address_space(3))) const unsigned short*)Vs;
        vs_lane = (unsigned)(unsigned long long)p3 + (unsigned)(g * 256 + c * 8);
    }

    const int j_start = (q0 >= WIN_) ? (q0 - WIN_) : 0;

    for (int j0 = j_start; j0 <= q0; j0 += 64) {
        __syncthreads();   // all waves done reading previous K/V tile
        // ---- stage K row-major and V column-blocks ----
        #pragma unroll
        for (int it = 0; it < 4; ++it) {
            int slot = tid + it * 256;
            int row  = slot >> 4;
            int d4   = (slot & 15) << 2;
            const __bf16* kp = qkv + (size_t)(b * T_ + j0 + row) * 3072 + 1024 + h * 64 + d4;
            *(ushort4*)&Ks[row * 72 + d4] = *(const ushort4*)kp;
            *(ushort4*)&Vs[(d4 >> 4) * 1040 + row * 16 + (d4 & 15)] = *(const ushort4*)(kp + 1024);
        }
        __syncthreads();

        // ---- S = Q K^T (scaled via Q) ----
        f32x4 sc[4];
        #pragma unroll
        for (int nt = 0; nt < 4; ++nt) {
            const bf16x8 b0 = *(const bf16x8*)&Ks[(nt * 16 + c) * 72 + g * 8];
            const bf16x8 b1 = *(const bf16x8*)&Ks[(nt * 16 + c) * 72 + 32 + g * 8];
            f32x4 s = {0.f, 0.f, 0.f, 0.f};
            s = mfma16(qa[0], b0, s);
            s = mfma16(qa[1], b1, s);
            sc[nt] = s;
        }

        // ---- band mask only where the tile touches a boundary (wave-uniform) ----
        const int rlo = q0 + w * 16;
        const bool need_mask = (j0 + 63 > rlo) || (rlo + 15 - j0 > WIN_);
        if (need_mask) {
            #pragma unroll
            for (int reg = 0; reg < 4; ++reg) {
                const int i_abs = rlo + g * 4 + reg;
                #pragma unroll
                for (int nt = 0; nt < 4; ++nt) {
                    int j_abs = j0 + nt * 16 + c;
                    bool ok = (j_abs <= i_abs) && (i_abs - j_abs <= WIN_);
                    sc[nt][reg] = ok ? sc[nt][reg] : -1e30f;
                }
            }
        }

        // ---- tile row-max ----
        float pmax[4];
        #pragma unroll
        for (int reg = 0; reg < 4; ++reg) {
            float bm = fmaxf(fmaxf(sc[0][reg], sc[1][reg]), fmaxf(sc[2][reg], sc[3][reg]));
            #pragma unroll
            for (int off = 1; off < 16; off <<= 1)
                bm = fmaxf(bm, __shfl_xor(bm, off));
            pmax[reg] = bm;
        }
        // ---- defer-max: rescale only if some row grew past THR=8 ----
        int need = 0;
        #pragma unroll
        for (int reg = 0; reg < 4; ++reg)
            need |= (pmax[reg] > m_run[reg] + 8.f) ? 1 : 0;
        if (__any(need)) {
            #pragma unroll
            for (int reg = 0; reg < 4; ++reg) {
                float mn = fmaxf(m_run[reg], pmax[reg]);
                float corr = __expf(m_run[reg] - mn);
                m_run[reg] = mn;
                l_run[reg] *= corr;
                #pragma unroll
                for (int dt = 0; dt < 4; ++dt) o[dt][reg] *= corr;
            }
        }
        // ---- P = exp(S - m); partial l; stage P (wave-local) ----
        #pragma unroll
        for (int reg = 0; reg < 4; ++reg) {
            #pragma unroll
            for (int nt = 0; nt < 4; ++nt) {
                float p = __expf(sc[nt][reg] - m_run[reg]);
                l_run[reg] += p;
                Ps[(w * 16 + g * 4 + reg) * 72 + nt * 16 + c] = f2b(p);
            }
        }

        // ---- O += P V : A-frags from Ps (b128), B-frags via tr-reads ----
        const bf16x8 pa0 = *(const bf16x8*)&Ps[(w * 16 + c) * 72 + g * 8];
        const bf16x8 pa1 = *(const bf16x8*)&Ps[(w * 16 + c) * 72 + 32 + g * 8];
        u32x2 t0[4], t1[4], t2[4], t3[4];
        #pragma unroll
        for (int dt = 0; dt < 4; ++dt) {
            unsigned va = vs_lane + dt * 2080;
            TR16(t0[dt], va, "0");      // rows g*8+0..3,  col c
            TR16(t1[dt], va, "128");    // rows g*8+4..7
            TR16(t2[dt], va, "1024");   // rows 32+g*8+0..3
            TR16(t3[dt], va, "1152");   // rows 32+g*8+4..7
        }
        asm volatile("s_waitcnt lgkmcnt(0)" ::: "memory");
        __builtin_amdgcn_sched_barrier(0);
        #pragma unroll
        for (int dt = 0; dt < 4; ++dt) {
            bf16x8 vb0 = combine_tr(t0[dt], t1[dt]);
            bf16x8 vb1 = combine_tr(t2[dt], t3[dt]);
            o[dt] = mfma16(pa0, vb0, o[dt]);
            o[dt] = mfma16(pa1, vb1, o[dt]);
        }
    }

    // ---- final: reduce partial l across the 16 c-lanes, write y ----
    float inv_l[4];
    #pragma unroll
    for (int reg = 0; reg < 4; ++reg) {
        float L = l_run[reg];
        #pragma unroll
        for (int off = 1; off < 16; off <<= 1)
            L += __shfl_xor(L, off);
        inv_l[reg] = 1.f / L;
    }
    #pragma unroll
    for (int dt = 0; dt < 4; ++dt)
        #pragma unroll
        for (int reg = 0; reg < 4; ++reg) {
            size_t row = (size_t)(b * T_ + q0 + w * 16 + g * 4 + reg);
            y[row * 1024 + h * 64 + dt * 16 + c] = (__bf16)(o[dt][reg] * inv_l[reg]);
        }
}

// ---------------- launch ----------------
extern "C" void kernel_launch(void* const* d_in, const int* in_sizes, int n_in,
                              void* d_out, int out_size, void* d_ws, size_t ws_size,
                              hipStream_t stream) {
    const float* x     = (const float*)d_in[0];
    const float* Wqkv  = (const float*)d_in[1];
    const float* Wproj = (const float*)d_in[2];
    const float* bproj = (const float*)d_in[3];
    float* out = (float*)d_out;

    char* p = (char*)d_ws;
    float*  cosT   = (float*)p;   p += (size_t)T_ * 32 * 4;
    float*  sinT   = (float*)p;   p += (size_t)T_ * 32 * 4;
    __bf16* xb     = (__bf16*)p;  p += (size_t)BT_ * 1024 * 2;
    __bf16* Wqkvb  = (__bf16*)p;  p += (size_t)3072 * 1024 * 2;
    __bf16* Wprojb = (__bf16*)p;  p += (size_t)1024 * 1024 * 2;
    __bf16* qkvb   = (__bf16*)p;  p += (size_t)BT_ * 3072 * 2;
    __bf16* yb     = (__bf16*)p;  p += (size_t)BT_ * 1024 * 2;

    rope_table_k<<<(T_ * 32) / 256, 256, 0, stream>>>(cosT, sinT);

    cvt_bf16_k<<<(BT_ * 1024 / 8) / 256, 256, 0, stream>>>(x, xb, BT_ * 1024 / 8);
    cvt_bf16_k<<<(3072 * 1024 / 8) / 256, 256, 0, stream>>>(Wqkv, Wqkvb, 3072 * 1024 / 8);
    cvt_bf16_k<<<(1024 * 1024 / 8) / 256, 256, 0, stream>>>(Wproj, Wprojb, 1024 * 1024 / 8);

    dim3 g1(3072 / 128, BT_ / 128);
    gemm_bt_mfma<true, true><<<g1, 256, 0, stream>>>(
        xb, Wqkvb, nullptr, qkvb, BT_, 3072, 1024, cosT, sinT);

    dim3 ga(T_ / 64, H_, B_);
    attn_k<<<ga, 256, 0, stream>>>(qkvb, yb);

    dim3 g2(1024 / 128, BT_ / 128);
    gemm_bt_mfma<false, false><<<g2, 256, 0, stream>>>(
        yb, Wprojb, bproj, out, BT_, 1024, 1024, nullptr, nullptr);
}

// Round 5
// 125.674 us; speedup vs baseline: 21.3653x; 1.1088x over previous
//
#include <hip/hip_runtime.h>
#include <math.h>

#define B_   2
#define T_   2048
#define C_   1024
#define H_   16
#define HD_  64
#define WIN_ 512
#define BT_  (B_ * T_)

typedef __bf16 bf16x8 __attribute__((ext_vector_type(8)));
typedef float  f32x4  __attribute__((ext_vector_type(4)));
typedef unsigned int u32x2 __attribute__((ext_vector_type(2)));
typedef unsigned short u16x8 __attribute__((ext_vector_type(8)));

__device__ __forceinline__ f32x4 mfma16(bf16x8 a, bf16x8 b, f32x4 c) {
    return __builtin_amdgcn_mfma_f32_16x16x32_bf16(a, b, c, 0, 0, 0);
}
__device__ __forceinline__ unsigned short f2b(float f) {
    __bf16 h = (__bf16)f;
    unsigned short u;
    __builtin_memcpy(&u, &h, 2);
    return u;
}
__device__ __forceinline__ void async_copy16(__bf16* lds, const __bf16* g) {
    __builtin_amdgcn_global_load_lds(
        (const __attribute__((address_space(1))) void*)g,
        (__attribute__((address_space(3))) void*)lds,
        16, 0, 0);
}

// hardware transpose read: lane l delivers column (l&15) of the 4x16 bf16
// tile at (per-lane vaddr); OFFLIT is a literal byte offset string.
#define TR16(dst, va, OFFLIT) \
    asm volatile("ds_read_b64_tr_b16 %0, %1 offset:" OFFLIT : "=v"(dst) : "v"(va))

__device__ __forceinline__ bf16x8 combine_tr(u32x2 a, u32x2 b) {
    union { unsigned u[4]; bf16x8 v; } x;
    x.u[0] = a[0]; x.u[1] = a[1]; x.u[2] = b[0]; x.u[3] = b[1];
    return x.v;
}

// ---------------- merged prep: 3x f32->bf16 convert + RoPE table ----------
__global__ void prep_k(const float* __restrict__ x, const float* __restrict__ Wqkv,
                       const float* __restrict__ Wproj,
                       __bf16* __restrict__ xb, __bf16* __restrict__ Wqkvb,
                       __bf16* __restrict__ Wprojb,
                       float* __restrict__ cosT, float* __restrict__ sinT) {
    const int gid = blockIdx.x * 256 + threadIdx.x;
    const int N0 = BT_ * 1024 / 8;          // x
    const int N1 = N0 + 3072 * 1024 / 8;    // Wqkv
    const int N2 = N1 + 1024 * 1024 / 8;    // Wproj
    const int N3 = N2 + T_ * 32 / 8;        // rope table
    if (gid < N2) {
        const float* src; __bf16* dst; int off;
        if (gid < N0)      { src = x;     dst = xb;     off = gid; }
        else if (gid < N1) { src = Wqkv;  dst = Wqkvb;  off = gid - N0; }
        else               { src = Wproj; dst = Wprojb; off = gid - N1; }
        float4 a = *(const float4*)&src[(size_t)off * 8];
        float4 b = *(const float4*)&src[(size_t)off * 8 + 4];
        bf16x8 o;
        o[0] = (__bf16)a.x; o[1] = (__bf16)a.y; o[2] = (__bf16)a.z; o[3] = (__bf16)a.w;
        o[4] = (__bf16)b.x; o[5] = (__bf16)b.y; o[6] = (__bf16)b.z; o[7] = (__bf16)b.w;
        *(bf16x8*)&dst[(size_t)off * 8] = o;
    } else if (gid < N3) {
        const int r = gid - N2;
        #pragma unroll
        for (int e = 0; e < 8; ++e) {
            int idx = r * 8 + e;
            int t = idx >> 5, j = idx & 31;
            float inv = powf(10000.0f, -(float)j / 32.0f);
            float f = (float)t * inv;
            cosT[idx] = cosf(f);
            sinT[idx] = sinf(f);
        }
    }
}

// ---------------- bf16 MFMA GEMM, double-buffered 2-phase prefetch ---------
// C = A @ B^T (+bias). ROPE: fused rotary embedding on cols < 2048.
template<bool OUT_BF16, bool ROPE>
__global__ __launch_bounds__(256) void gemm_bt_mfma(
        const __bf16* __restrict__ A, const __bf16* __restrict__ Bm,
        const float* __restrict__ bias, void* __restrict__ Cv,
        int M, int N, int K,
        const float* __restrict__ cosT, const float* __restrict__ sinT)
{
    __shared__ __bf16 As[2][128 * 32];
    __shared__ __bf16 Bs[2][128 * 32];
    const int tid  = threadIdx.x;
    const int w    = tid >> 6;
    const int lane = tid & 63;
    const int c    = lane & 15;
    const int g    = lane >> 4;
    const int bm0  = blockIdx.y * 128;
    const int bn0  = blockIdx.x * 128;
    const int wm0  = (w >> 1) * 64;
    const int wn0  = (w & 1) * 64;

    f32x4 acc[4][4] = {};

    auto stage = [&](int buf, int k0) {
        #pragma unroll
        for (int it = 0; it < 2; ++it) {
            int slot = it * 256 + tid;
            int r    = slot >> 2;
            int c8   = (slot & 3) * 8;
            async_copy16(&As[buf][slot * 8], &A[(size_t)(bm0 + r) * K + k0 + c8]);
            async_copy16(&Bs[buf][slot * 8], &Bm[(size_t)(bn0 + r) * K + k0 + c8]);
        }
    };

    stage(0, 0);
    int cur = 0;
    for (int k0 = 0; k0 < K; k0 += 32) {
        __syncthreads();                    // drains vmcnt -> buf[cur] ready
        if (k0 + 32 < K) stage(cur ^ 1, k0 + 32);   // prefetch next tile
        bf16x8 af[4], bfr[4];
        #pragma unroll
        for (int m = 0; m < 4; ++m)
            af[m] = *(const bf16x8*)&As[cur][(wm0 + m * 16 + c) * 32 + g * 8];
        #pragma unroll
        for (int n = 0; n < 4; ++n)
            bfr[n] = *(const bf16x8*)&Bs[cur][(wn0 + n * 16 + c) * 32 + g * 8];
        #pragma unroll
        for (int m = 0; m < 4; ++m)
            #pragma unroll
            for (int n = 0; n < 4; ++n)
                acc[m][n] = mfma16(af[m], bfr[n], acc[m][n]);
        cur ^= 1;
    }

    if (ROPE) {
        #pragma unroll
        for (int m = 0; m < 4; ++m) {
            #pragma unroll
            for (int r2 = 0; r2 < 4; ++r2) {
                const int row = bm0 + wm0 + m * 16 + g * 4 + r2;
                const int t = row & (T_ - 1);
                #pragma unroll
                for (int n = 0; n < 4; ++n) {
                    const int cbase = bn0 + wn0 + n * 16;
                    const int cc = cbase + c;
                    float v = acc[m][n][r2];
                    float outv;
                    if (cbase < 2048) {   // q or k region (uniform branch)
                        float prt = __shfl_xor(v, 1);
                        int jj = (cc & 63) >> 1;
                        float cs = cosT[t * 32 + jj];
                        float sn = sinT[t * 32 + jj];
                        outv = (cc & 1) ? (v * cs + prt * sn) : (v * cs - prt * sn);
                    } else {
                        outv = v;
                    }
                    ((__bf16*)Cv)[(size_t)row * N + cc] = (__bf16)outv;
                }
            }
        }
    } else {
        #pragma unroll
        for (int m = 0; m < 4; ++m) {
            int rr = bm0 + wm0 + m * 16 + g * 4;
            #pragma unroll
            for (int n = 0; n < 4; ++n) {
                int cc = bn0 + wn0 + n * 16 + c;
                float bv = (!OUT_BF16 && bias) ? bias[cc] : 0.f;
                #pragma unroll
                for (int r2 = 0; r2 < 4; ++r2) {
                    float v = acc[m][n][r2] + bv;
                    if (OUT_BF16) ((__bf16*)Cv)[(size_t)(rr + r2) * N + cc] = (__bf16)v;
                    else          ((float*)Cv)[(size_t)(rr + r2) * N + cc] = v;
                }
            }
        }
    }
}

// ---------------- banded flash attention, MFMA bf16 ------------------------
// K: [64][72] row-major; V: 4 column-blocks [64][16] (stride 1040 shorts),
// consumed via ds_read_b64_tr_b16; P: [64][72] wave-local.
// T14: K/V of tile t+1 loaded to regs during tile t compute, LDS-written
// after the barrier. XCD swizzle clusters same-(b,h) blocks per XCD.
__global__ __launch_bounds__(256) void attn_k(const __bf16* __restrict__ qkv,
                                              __bf16* __restrict__ y)
{
    __shared__ __align__(16) unsigned short Ks[64 * 72];
    __shared__ __align__(16) unsigned short Ps[64 * 72];
    __shared__ __align__(16) unsigned short Vs[4 * 1040];

    const int tid  = threadIdx.x;
    const int lane = tid & 63;
    const int w    = tid >> 6;
    const int c    = lane & 15;
    const int g    = lane >> 4;

    // bijective XCD swizzle: 1024 blocks = 8 XCDs x 128
    const int bid = blockIdx.x;
    const int swz = (bid & 7) * 128 + (bid >> 3);
    const int q0 = (swz & 31) * 64;
    const int hb = swz >> 5;            // [0,32)
    const int h  = hb & 15;
    const int b  = hb >> 4;

    // ---- Q fragments, pre-scaled by 1/sqrt(64) ----
    bf16x8 qa[2];
    {
        const int qrow = q0 + w * 16 + c;
        const __bf16* qp = qkv + (size_t)(b * T_ + qrow) * 3072 + h * 64 + g * 8;
        bf16x8 r0 = *(const bf16x8*)qp;
        bf16x8 r1 = *(const bf16x8*)(qp + 32);
        #pragma unroll
        for (int e = 0; e < 8; ++e) {
            qa[0][e] = (__bf16)((float)r0[e] * 0.125f);
            qa[1][e] = (__bf16)((float)r1[e] * 0.125f);
        }
    }

    float m_run[4] = {-1e30f, -1e30f, -1e30f, -1e30f};
    float l_run[4] = {0.f, 0.f, 0.f, 0.f};
    f32x4 o[4] = {};

    unsigned vs_lane;
    {
        auto* p3 = (__attribute__((address_space(3))) const unsigned short*)Vs;
        vs_lane = (unsigned)(unsigned long long)p3 + (unsigned)(g * 256 + c * 8);
    }

    // staging geometry: slot in [0,512), row = slot>>3, d8 = (slot&7)*8
    const int r0s = tid >> 3,          d80 = (tid & 7) * 8;
    const int r1s = (tid + 256) >> 3,  d81 = d80;   // (slot+256)&7 == slot&7
    const size_t kbase = (size_t)(b * T_) * 3072 + 1024 + h * 64;

    const int j_start = (q0 >= WIN_) ? (q0 - WIN_) : 0;

    // ---- prologue: load tile j_start into regs ----
    u16x8 kr0, kr1, vr0, vr1;
    {
        const __bf16* p0 = qkv + kbase + (size_t)(j_start + r0s) * 3072 + d80;
        const __bf16* p1 = qkv + kbase + (size_t)(j_start + r1s) * 3072 + d81;
        kr0 = *(const u16x8*)p0;  vr0 = *(const u16x8*)(p0 + 1024);
        kr1 = *(const u16x8*)p1;  vr1 = *(const u16x8*)(p1 + 1024);
    }

    for (int j0 = j_start; j0 <= q0; j0 += 64) {
        __syncthreads();   // all waves done reading previous K/V tile
        // ---- write staged regs -> LDS ----
        {
            union { u16x8 v; ushort4 h[2]; } u;
            u.v = kr0;
            *(ushort4*)&Ks[r0s * 72 + d80]     = u.h[0];
            *(ushort4*)&Ks[r0s * 72 + d80 + 4] = u.h[1];
            u.v = kr1;
            *(ushort4*)&Ks[r1s * 72 + d81]     = u.h[0];
            *(ushort4*)&Ks[r1s * 72 + d81 + 4] = u.h[1];
            *(u16x8*)&Vs[(d80 >> 4) * 1040 + r0s * 16 + (d80 & 15)] = vr0;
            *(u16x8*)&Vs[(d81 >> 4) * 1040 + r1s * 16 + (d81 & 15)] = vr1;
        }
        __syncthreads();

        // ---- issue next tile's loads (latency hides under compute) ----
        if (j0 + 64 <= q0) {
            const __bf16* p0 = qkv + kbase + (size_t)(j0 + 64 + r0s) * 3072 + d80;
            const __bf16* p1 = qkv + kbase + (size_t)(j0 + 64 + r1s) * 3072 + d81;
            kr0 = *(const u16x8*)p0;  vr0 = *(const u16x8*)(p0 + 1024);
            kr1 = *(const u16x8*)p1;  vr1 = *(const u16x8*)(p1 + 1024);
        }

        // ---- S = Q K^T (scaled via Q) ----
        f32x4 sc[4];
        __builtin_amdgcn_s_setprio(1);
        #pragma unroll
        for (int nt = 0; nt < 4; ++nt) {
            const bf16x8 b0 = *(const bf16x8*)&Ks[(nt * 16 + c) * 72 + g * 8];
            const bf16x8 b1 = *(const bf16x8*)&Ks[(nt * 16 + c) * 72 + 32 + g * 8];
            f32x4 s = {0.f, 0.f, 0.f, 0.f};
            s = mfma16(qa[0], b0, s);
            s = mfma16(qa[1], b1, s);
            sc[nt] = s;
        }
        __builtin_amdgcn_s_setprio(0);

        // ---- band mask only where the tile touches a boundary ----
        const int rlo = q0 + w * 16;
        const bool need_mask = (j0 + 63 > rlo) || (rlo + 15 - j0 > WIN_);
        if (need_mask) {
            #pragma unroll
            for (int reg = 0; reg < 4; ++reg) {
                const int i_abs = rlo + g * 4 + reg;
                #pragma unroll
                for (int nt = 0; nt < 4; ++nt) {
                    int j_abs = j0 + nt * 16 + c;
                    bool ok = (j_abs <= i_abs) && (i_abs - j_abs <= WIN_);
                    sc[nt][reg] = ok ? sc[nt][reg] : -1e30f;
                }
            }
        }

        // ---- tile row-max ----
        float pmax[4];
        #pragma unroll
        for (int reg = 0; reg < 4; ++reg) {
            float bm = fmaxf(fmaxf(sc[0][reg], sc[1][reg]), fmaxf(sc[2][reg], sc[3][reg]));
            #pragma unroll
            for (int off = 1; off < 16; off <<= 1)
                bm = fmaxf(bm, __shfl_xor(bm, off));
            pmax[reg] = bm;
        }
        // ---- defer-max: rescale only if some row grew past THR=8 ----
        int need = 0;
        #pragma unroll
        for (int reg = 0; reg < 4; ++reg)
            need |= (pmax[reg] > m_run[reg] + 8.f) ? 1 : 0;
        if (__any(need)) {
            #pragma unroll
            for (int reg = 0; reg < 4; ++reg) {
                float mn = fmaxf(m_run[reg], pmax[reg]);
                float corr = __expf(m_run[reg] - mn);
                m_run[reg] = mn;
                l_run[reg] *= corr;
                #pragma unroll
                for (int dt = 0; dt < 4; ++dt) o[dt][reg] *= corr;
            }
        }
        // ---- P = exp(S - m); partial l; stage P (wave-local) ----
        #pragma unroll
        for (int reg = 0; reg < 4; ++reg) {
            #pragma unroll
            for (int nt = 0; nt < 4; ++nt) {
                float p = __expf(sc[nt][reg] - m_run[reg]);
                l_run[reg] += p;
                Ps[(w * 16 + g * 4 + reg) * 72 + nt * 16 + c] = f2b(p);
            }
        }

        // ---- O += P V : A-frags from Ps (b128), B-frags via tr-reads ----
        const bf16x8 pa0 = *(const bf16x8*)&Ps[(w * 16 + c) * 72 + g * 8];
        const bf16x8 pa1 = *(const bf16x8*)&Ps[(w * 16 + c) * 72 + 32 + g * 8];
        u32x2 t0[4], t1[4], t2[4], t3[4];
        #pragma unroll
        for (int dt = 0; dt < 4; ++dt) {
            unsigned va = vs_lane + dt * 2080;
            TR16(t0[dt], va, "0");
            TR16(t1[dt], va, "128");
            TR16(t2[dt], va, "1024");
            TR16(t3[dt], va, "1152");
        }
        asm volatile("s_waitcnt lgkmcnt(0)" ::: "memory");
        __builtin_amdgcn_sched_barrier(0);
        __builtin_amdgcn_s_setprio(1);
        #pragma unroll
        for (int dt = 0; dt < 4; ++dt) {
            bf16x8 vb0 = combine_tr(t0[dt], t1[dt]);
            bf16x8 vb1 = combine_tr(t2[dt], t3[dt]);
            o[dt] = mfma16(pa0, vb0, o[dt]);
            o[dt] = mfma16(pa1, vb1, o[dt]);
        }
        __builtin_amdgcn_s_setprio(0);
    }

    // ---- final: reduce partial l across the 16 c-lanes, write y ----
    float inv_l[4];
    #pragma unroll
    for (int reg = 0; reg < 4; ++reg) {
        float L = l_run[reg];
        #pragma unroll
        for (int off = 1; off < 16; off <<= 1)
            L += __shfl_xor(L, off);
        inv_l[reg] = 1.f / L;
    }
    #pragma unroll
    for (int dt = 0; dt < 4; ++dt)
        #pragma unroll
        for (int reg = 0; reg < 4; ++reg) {
            size_t row = (size_t)(b * T_ + q0 + w * 16 + g * 4 + reg);
            y[row * 1024 + h * 64 + dt * 16 + c] = (__bf16)(o[dt][reg] * inv_l[reg]);
        }
}

// ---------------- launch ----------------
extern "C" void kernel_launch(void* const* d_in, const int* in_sizes, int n_in,
                              void* d_out, int out_size, void* d_ws, size_t ws_size,
                              hipStream_t stream) {
    const float* x     = (const float*)d_in[0];
    const float* Wqkv  = (const float*)d_in[1];
    const float* Wproj = (const float*)d_in[2];
    const float* bproj = (const float*)d_in[3];
    float* out = (float*)d_out;

    char* p = (char*)d_ws;
    float*  cosT   = (float*)p;   p += (size_t)T_ * 32 * 4;
    float*  sinT   = (float*)p;   p += (size_t)T_ * 32 * 4;
    __bf16* xb     = (__bf16*)p;  p += (size_t)BT_ * 1024 * 2;
    __bf16* Wqkvb  = (__bf16*)p;  p += (size_t)3072 * 1024 * 2;
    __bf16* Wprojb = (__bf16*)p;  p += (size_t)1024 * 1024 * 2;
    __bf16* qkvb   = (__bf16*)p;  p += (size_t)BT_ * 3072 * 2;
    __bf16* yb     = (__bf16*)p;  p += (size_t)BT_ * 1024 * 2;

    const int nprep = (BT_ * 1024 + 3072 * 1024 + 1024 * 1024) / 8 + T_ * 32 / 8;
    prep_k<<<(nprep + 255) / 256, 256, 0, stream>>>(
        x, Wqkv, Wproj, xb, Wqkvb, Wprojb, cosT, sinT);

    dim3 g1(3072 / 128, BT_ / 128);
    gemm_bt_mfma<true, true><<<g1, 256, 0, stream>>>(
        xb, Wqkvb, nullptr, qkvb, BT_, 3072, 1024, cosT, sinT);

    attn_k<<<(T_ / 64) * H_ * B_, 256, 0, stream>>>(qkvb, yb);

    dim3 g2(1024 / 128, BT_ / 128);
    gemm_bt_mfma<false, false><<<g2, 256, 0, stream>>>(
        yb, Wprojb, bproj, out, BT_, 1024, 1024, nullptr, nullptr);
}